// Round 17
// baseline (10923.593 us; speedup 1.0000x reference)
//
#include <hip/hip_runtime.h>

typedef __attribute__((ext_vector_type(8))) short short8;
typedef __attribute__((ext_vector_type(4))) float f32x4;
typedef unsigned short ushort_t;
typedef unsigned long long u64_t;

#define T_STEPS 1024
#define NWG 68
#define NWG_MT 17

// r17 = r16 with __launch_bounds__(512, 1): r16's (512,2) capped VGPR at 128,
// spilling the 208-VGPR register-resident weight array to scratch (VGPR_Count
// counter showed 128; dur regressed 6.65->10.9ms). (512,1) allows 256 VGPR ->
// the measured 204/wave fits. 17 WGs/mtile (L0 r=0..4, L1 r=5..8, L2 r=9..16),
// each WG 4 tiles (8 waves = 4 wave-pairs, r13 spans 13/13, 9/8, 12/11 kb).
// 4-deep h buffers; spread wf flags; pre-wait only:
//   L0: wf[0,5) >= s ; wf[5,9)  >= s-2
//   L1: wf[0,9) >= s ; wf[9,17) >= s-2
//   L2: wf[5,17) >= s
// (audit as r16: all RAW covered by >=s ranges; WAR by >=s-2 with 4-deep bufs)

#define PACK0 0
#define PACK1 1064960            // 20*26*2048
#define PACK2 1517568            // PACK1 + 13*17*2048

#define HI_P (64*320)
#define HC_P (64*224)
#define HM_P (64*512)

// ws offsets (bytes)
#define WS_BAR   0               // 4 mtiles x 4KB spread flags
#define WS_MU    16384
#define WS_RSTD  278528
#define WS_HI    540672          // 4*HI_P*2 = 163840 -> 704512
#define WS_HC    704512          // 4*HC_P*2 = 114688 -> 819200
#define WS_HM    819200          // 4*HM_P*2 = 262144 -> 1081344
#define WS_PACK  1081344         // + 6049792 -> ends 7131136

__device__ __forceinline__ ushort_t f2bf(float f) {
  union { float f; unsigned u; } un; un.f = f;
  unsigned r = (un.u + 0x7fffu + ((un.u >> 16) & 1u)) >> 16;
  return (ushort_t)r;
}

__device__ __forceinline__ void st2(ushort_t* p, ushort_t v) {
  __hip_atomic_store(p, v, __ATOMIC_RELAXED, __HIP_MEMORY_SCOPE_SYSTEM);
}
__device__ __forceinline__ u64_t ld8(const ushort_t* p) {
  return __hip_atomic_load((const u64_t*)p, __ATOMIC_RELAXED, __HIP_MEMORY_SCOPE_SYSTEM);
}
__device__ __forceinline__ unsigned ldf(const unsigned* p) {
  return __hip_atomic_load(p, __ATOMIC_RELAXED, __HIP_MEMORY_SCOPE_SYSTEM);
}
__device__ __forceinline__ void stf(unsigned* p, unsigned v) {
  __hip_atomic_store(p, v, __ATOMIC_RELAXED, __HIP_MEMORY_SCOPE_SYSTEM);
}

// ---------------- LayerNorm stats ----------------
__global__ __launch_bounds__(256) void ln_stats(const float* __restrict__ x,
                                                float* __restrict__ mu,
                                                float* __restrict__ rstd) {
  const int row = blockIdx.x * 4 + (threadIdx.x >> 6);
  const int lane = threadIdx.x & 63;
  const float* xr = x + (size_t)row * 512;
  float4 v0 = *(const float4*)(xr + lane * 8);
  float4 v1 = *(const float4*)(xr + lane * 8 + 4);
  float s = v0.x + v0.y + v0.z + v0.w + v1.x + v1.y + v1.z + v1.w;
  float q = v0.x*v0.x + v0.y*v0.y + v0.z*v0.z + v0.w*v0.w
          + v1.x*v1.x + v1.y*v1.y + v1.z*v1.z + v1.w*v1.w;
  for (int m = 1; m <= 32; m <<= 1) {
    s += __shfl_xor(s, m, 64);
    q += __shfl_xor(q, m, 64);
  }
  if (lane == 0) {
    float mean = s * (1.f / 512.f);
    float var = q * (1.f / 512.f) - mean * mean;
    mu[row] = mean;
    rstd[row] = rsqrtf(var + 1e-5f);
  }
}

// -------- init hidden state: bf16 linear padded, ALL FOUR parities --------
__global__ void init_h(const float* __restrict__ h0,
                       ushort_t* hi, ushort_t* hc, ushort_t* hm) {
  int i = blockIdx.x * 256 + threadIdx.x;
  if (i >= 64 * 1056) return;
  int b = i / 1056, c = i % 1056;
  if (c < 320) {
    ushort_t v = (c < 308) ? f2bf(h0[b * 1024 + c]) : 0;
#pragma unroll
    for (int p = 0; p < 4; ++p) st2(hi + p * HI_P + b * 320 + c, v);
  } else if (c < 544) {
    int col = c - 320;
    ushort_t v = (col < 204) ? f2bf(h0[b * 1024 + 308 + col]) : 0;
#pragma unroll
    for (int p = 0; p < 4; ++p) st2(hc + p * HC_P + b * 224 + col, v);
  } else {
    int col = c - 544;
    ushort_t v = f2bf(h0[b * 1024 + 512 + col]);
#pragma unroll
    for (int p = 0; p < 4; ++p) st2(hm + p * HM_P + b * 512 + col, v);
  }
}

// ---------------- pack masked weights ----------------
struct PackP {
  const float* w[12];
  const float* msk[3];
  ushort_t* pack;
};

__global__ __launch_bounds__(256) void ncp_pack(PackP P) {
  int u = blockIdx.x * 256 + threadIdx.x;
  int layer, rem, KB, K, H, s0p, s0l, s1l;
  size_t base;
  if (u < 133120)      { layer = 0; rem = u;          KB = 26; K = 820; H = 308; s0p = 512; s0l = 512; s1l = 308; base = PACK0; }
  else if (u < 189696) { layer = 1; rem = u - 133120; KB = 17; K = 512; H = 204; s0p = 320; s0l = 308; s1l = 204; base = PACK1; }
  else if (u < 378112) { layer = 2; rem = u - 189696; KB = 23; K = 716; H = 512; s0p = 224; s0l = 204; s1l = 512; base = PACK2; }
  else return;
  const int lane = rem & 63;
  const int mat = (rem >> 6) & 3;
  const int kb = (rem >> 8) % KB;
  const int nt = (rem >> 8) / KB;
  const float* W = P.w[layer * 4 + mat];
  const float* M = (mat < 2) ? P.msk[layer] : nullptr;
  const int n = nt * 16 + (lane & 15);
  const int kbase = kb * 32 + ((lane >> 4) << 3);
  ushort_t* dst = P.pack + base + (size_t)rem * 8;
#pragma unroll
  for (int j = 0; j < 8; ++j) {
    const int kp = kbase + j;
    int ko;
    if (kp < s0p) ko = (kp < s0l) ? kp : -1;
    else { const int ks = kp - s0p; ko = (ks < s1l) ? (s0l + ks) : -1; }
    float v = 0.f;
    if (n < H && ko >= 0) {
      v = W[(size_t)n * K + ko];
      if (M) v *= M[(size_t)n * K + ko];
    }
    dst[j] = f2bf(v);
  }
}

// ---------------- main persistent kernel ----------------
struct MainP {
  const float* x;
  const float* gamma;
  const float* beta;
  const float* bias[12];
  const float* mu;
  const float* rstd;
  ushort_t* hi;
  ushort_t* hc;
  ushort_t* hm;
  const ushort_t* pack;
  unsigned* bar;
  float* y;
  float* hfin;
};

#define MAXKB 13

template<int KBT>
__device__ __forceinline__ void load_w(const ushort_t* __restrict__ bp, int lane,
                                       short8 (*w)[4]) {
#pragma unroll
  for (int kb = 0; kb < KBT; ++kb) {
    const ushort_t* q = bp + (size_t)kb * 2048 + lane * 8;
    w[kb][0] = *(const short8*)(q);
    w[kb][1] = *(const short8*)(q + 512);
    w[kb][2] = *(const short8*)(q + 1024);
    w[kb][3] = *(const short8*)(q + 1536);
  }
}

template<int KBT>
__device__ __forceinline__ void span_reg(const short8 (*w)[4],
                                         const ushort_t* __restrict__ lds, int lane,
                                         f32x4& a0, f32x4& a1, f32x4& a2, f32x4& a3) {
#pragma unroll
  for (int kb = 0; kb < KBT; ++kb) {
    short8 av = *(const short8*)(lds + (size_t)(kb * 64 + lane) * 8);
    a0 = __builtin_amdgcn_mfma_f32_16x16x32_bf16(av, w[kb][0], a0, 0, 0, 0);
    a1 = __builtin_amdgcn_mfma_f32_16x16x32_bf16(av, w[kb][1], a1, 0, 0, 0);
    a2 = __builtin_amdgcn_mfma_f32_16x16x32_bf16(av, w[kb][2], a2, 0, 0, 0);
    a3 = __builtin_amdgcn_mfma_f32_16x16x32_bf16(av, w[kb][3], a3, 0, 0, 0);
  }
}

template<int H, int STP>
__device__ __forceinline__ void epi_h(const f32x4* A, int nt, int lane, int mtile,
                                      const float* __restrict__ bp1, const float* __restrict__ bp2,
                                      const float* __restrict__ bpa, const float* __restrict__ bpb,
                                      ushort_t* __restrict__ hout, float* vk) {
  const int n = nt * 16 + (lane & 15);
  const int r0 = (lane >> 4) << 2;
#pragma unroll
  for (int j = 0; j < 4; ++j) vk[j] = 0.f;
  if (n < H) {
    float c1 = bp1[n], c2 = bp2[n], ca = bpa[n], cb = bpb[n];
#pragma unroll
    for (int j = 0; j < 4; ++j) {
      int brow = mtile * 16 + r0 + j;
      float sg = 1.f / (1.f + __expf(-(A[2][j] + ca + A[3][j] + cb)));
      float f1 = 1.f - 2.f / (1.f + __expf(2.f * (A[0][j] + c1)));
      float f2 = 1.f - 2.f / (1.f + __expf(2.f * (A[1][j] + c2)));
      float v = f1 * (1.f - sg) + sg * f2;
      vk[j] = v;
      st2(hout + (size_t)brow * STP + n, f2bf(v));
    }
  }
}

// stage up to two bf16 padded segments with 512 threads; coalesced 8B units,
// all loads issued before any LDS write.
template<int S1, int ST1, int S2, int ST2>
__device__ __forceinline__ void stage2(ushort_t* __restrict__ r1, const ushort_t* __restrict__ h1,
                                       ushort_t* __restrict__ r2, const ushort_t* __restrict__ h2,
                                       int tid) {
  constexpr int U1 = S1 * 2, U2 = S2 * 2;
  constexpr int I1 = (U1 + 511) / 512;
  constexpr int I2 = (U2 + 511) / 512;
  u64_t a[I1];
  u64_t b[I2 > 0 ? I2 : 1];
#pragma unroll
  for (int i = 0; i < I1; ++i) {
    const int u = tid + i * 512;
    if ((U1 & 511) == 0 || u < U1) {
      const int slot = u >> 1;
      a[i] = ld8(h1 + (slot & 15) * ST1 + (slot >> 6) * 32 + ((slot >> 4) & 3) * 8 + (u & 1) * 4);
    }
  }
  if constexpr (S2 > 0) {
#pragma unroll
    for (int i = 0; i < I2; ++i) {
      const int u = tid + i * 512;
      if ((U2 & 511) == 0 || u < U2) {
        const int slot = u >> 1;
        b[i] = ld8(h2 + (slot & 15) * ST2 + (slot >> 6) * 32 + ((slot >> 4) & 3) * 8 + (u & 1) * 4);
      }
    }
  }
#pragma unroll
  for (int i = 0; i < I1; ++i) {
    const int u = tid + i * 512;
    if ((U1 & 511) == 0 || u < U1) *(u64_t*)(r1 + (size_t)u * 4) = a[i];
  }
  if constexpr (S2 > 0) {
#pragma unroll
    for (int i = 0; i < I2; ++i) {
      const int u = tid + i * 512;
      if ((U2 & 511) == 0 || u < U2) *(u64_t*)(r2 + (size_t)u * 4) = b[i];
    }
  }
}

__device__ __forceinline__ void stage_xn(ushort_t* __restrict__ XN, const MainP& P,
                                         int mtile, int tid, int t) {
#pragma unroll
  for (int i = 0; i < 2; ++i) {
    const int s = tid + i * 512;
    const int ln = s & 63;
    const int brow = mtile * 16 + (ln & 15);
    const int kbase = (s >> 6) * 32 + ((ln >> 4) << 3);
    const float muv = P.mu[brow * T_STEPS + t];
    const float rsv = P.rstd[brow * T_STEPS + t];
    const f32x4* xr = (const f32x4*)(P.x + ((size_t)brow * T_STEPS + t) * 512 + kbase);
    f32x4 xv0 = __builtin_nontemporal_load(xr);
    f32x4 xv1 = __builtin_nontemporal_load(xr + 1);
    const f32x4 g0 = *(const f32x4*)(P.gamma + kbase);
    const f32x4 g1 = *(const f32x4*)(P.gamma + kbase + 4);
    const f32x4 b0 = *(const f32x4*)(P.beta + kbase);
    const f32x4 b1 = *(const f32x4*)(P.beta + kbase + 4);
    short8 w;
#pragma unroll
    for (int j = 0; j < 4; ++j) w[j] = f2bf((xv0[j] - muv) * rsv * g0[j] + b0[j]);
#pragma unroll
    for (int j = 0; j < 4; ++j) w[4 + j] = f2bf((xv1[j] - muv) * rsv * g1[j] + b1[j]);
    *(short8*)(XN + (size_t)s * 8) = w;
  }
}

// wave poll: two flag ranges with separate thresholds; s_sleep(1) backoff
__device__ __forceinline__ void poll2(const unsigned* wfbase, int lane,
                                      int a1, int c1, unsigned need1,
                                      int a2, int c2, unsigned need2) {
  const unsigned* p = wfbase;
  unsigned need = 0;
  bool act = false;
  if (lane < c1)           { p = wfbase + (a1 + lane) * 16;        need = need1; act = true; }
  else if (lane < c1 + c2) { p = wfbase + (a2 + lane - c1) * 16;   need = need2; act = true; }
  for (;;) {
    unsigned v = act ? ldf(p) : 0xFFFFFFFFu;
    if (__all((int)(v >= need))) break;
    __builtin_amdgcn_s_sleep(1);
  }
}

__global__ __launch_bounds__(512, 1) void ncp_main(MainP P) {
  const int tid = threadIdx.x;
  const int lane = tid & 63;
  const int wv = tid >> 6;        // 0..7
  const int role = wv & 1;        // span half within the tile
  const int tslot = wv >> 1;      // which of the WG's 4 tiles
  const int wg = blockIdx.x;
  const int mt = wg / NWG_MT;     // 0..3
  const int r  = wg % NWG_MT;     // 0..4: L0, 5..8: L1, 9..16: L2

  __shared__ __align__(16) ushort_t Alds[2688 * 8];  // 42 KB staging (L0 layout)
  __shared__ __align__(16) f32x4 pacc[4][256];       // 16 KB partials (dense)

  // ---- spread flags: wf[r*16], mtile stride 1024 unsigned (4KB) ----
  unsigned* wf = P.bar + mt * 1024;
  int a1, c1, a2, c2;             // (a1,c1)@>=s  (a2,c2)@>=s-2
  if (r < 5)       { a1 = 0; c1 = 5;  a2 = 5; c2 = 4; }
  else if (r < 9)  { a1 = 0; c1 = 9;  a2 = 9; c2 = 8; }
  else             { a1 = 5; c1 = 12; a2 = 0; c2 = 0; }

  // ---- per-wave tile/validity ----
  int nt = 0;
  bool valid = true;
  if (r < 5)       nt = r * 4 + tslot;
  else if (r < 9)  { nt = (r - 5) * 4 + tslot; valid = (nt < 13); }
  else             nt = (r - 9) * 4 + tslot;

  // ---- one-time weight preload into registers (r13 spans) ----
  short8 wreg[MAXKB][4];
  if (valid) {
    if (r < 5) {
      const ushort_t* bp = P.pack + PACK0 + (size_t)nt * 26 * 2048 + (role ? 13 : 0) * 2048;
      load_w<13>(bp, lane, wreg);
    } else if (r < 9) {
      const ushort_t* bp = P.pack + PACK1 + (size_t)nt * 17 * 2048;
      if (role == 0) load_w<9>(bp, lane, wreg);
      else           load_w<8>(bp + 9 * 2048, lane, wreg);
    } else {
      const ushort_t* bp = P.pack + PACK2 + (size_t)nt * 23 * 2048;
      if (role == 0) load_w<12>(bp, lane, wreg);
      else           load_w<11>(bp + 12 * 2048, lane, wreg);
    }
  }

  if (r < 5) stage_xn(Alds, P, mt, tid, 0);  // prologue XN(0) into parity-0

  for (int s = 0; s < T_STEPS + 2; ++s) {
    // ---- pre-wait: RAW >= s, relaxed WAR >= s-2 (single poll) ----
    if (wv == 0) {
      const unsigned needA = (unsigned)s;
      const unsigned needB = (s >= 2) ? (unsigned)(s - 2) : 0u;
      poll2(wf, lane, a1, c1, needA, a2, c2, needB);
    }
    __syncthreads();

    // ---- per-layer slot state ----
    int tstep = 0;
    bool on = false;
    if (r < 5)       { tstep = s;     on = (s < T_STEPS); }
    else if (r < 9)  { tstep = s - 1; on = (s >= 1 && s <= T_STEPS) && valid; }
    else             { tstep = s - 2; on = (s >= 2); }
    const bool last = (tstep == T_STEPS - 1);

    // ---- stage (4-deep parity) ----
    if (r < 5) {
      if (s < T_STEPS)
        stage2<640, 320, 0, 0>(Alds + 2048 * 8,
                               P.hi + (((s - 1) & 3) * 64 + mt * 16) * 320,
                               nullptr, nullptr, tid);
    } else if (r < 9) {
      if (s >= 1 && s <= T_STEPS)
        stage2<640, 320, 448, 224>(Alds, P.hi + (((s - 1) & 3) * 64 + mt * 16) * 320,
                                   Alds + 640 * 8,
                                   P.hc + (((s - 2) & 3) * 64 + mt * 16) * 224, tid);
    } else {
      if (s >= 2)
        stage2<448, 224, 1024, 512>(Alds, P.hc + (((s - 2) & 3) * 64 + mt * 16) * 224,
                                    Alds + 448 * 8,
                                    P.hm + (((s - 3) & 3) * 64 + mt * 16) * 512, tid);
    }
    __syncthreads();                      // (A) LDS staged

    // ---- spans (register-resident weights) ----
    f32x4 A[4];
#pragma unroll
    for (int j = 0; j < 4; ++j) A[j] = {0.f, 0.f, 0.f, 0.f};
    if (on) {
      if (r < 5) {
        const ushort_t* XNc = Alds + (s & 1) * (1024 * 8);
        const ushort_t* HIl = Alds + 2048 * 8;
        if (role == 0) span_reg<13>(wreg, XNc, lane, A[0], A[1], A[2], A[3]);
        else { span_reg<3>(wreg, XNc + 13 * 512, lane, A[0], A[1], A[2], A[3]);
               span_reg<10>(wreg + 3, HIl, lane, A[0], A[1], A[2], A[3]); }
      } else if (r < 9) {
        const ushort_t* HIr = Alds;
        const ushort_t* HCr = Alds + 640 * 8;
        if (role == 0) span_reg<9>(wreg, HIr, lane, A[0], A[1], A[2], A[3]);
        else { span_reg<1>(wreg, HIr + 9 * 512, lane, A[0], A[1], A[2], A[3]);
               span_reg<7>(wreg + 1, HCr, lane, A[0], A[1], A[2], A[3]); }
      } else {
        const ushort_t* HCr = Alds;
        const ushort_t* HMr = Alds + 448 * 8;
        if (role == 0) { span_reg<7>(wreg, HCr, lane, A[0], A[1], A[2], A[3]);
                         span_reg<5>(wreg + 7, HMr, lane, A[0], A[1], A[2], A[3]); }
        else           span_reg<11>(wreg, HMr + 5 * 512, lane, A[0], A[1], A[2], A[3]);
      }
      if (role == 1) {
#pragma unroll
        for (int j = 0; j < 4; ++j) pacc[tslot][j * 64 + lane] = A[j];
      }
    }
    __syncthreads();                      // (A2) partner accumulator ready

    // ---- epilogue: h-stores only ----
    float vk[4];
    if (on && role == 0) {
#pragma unroll
      for (int j = 0; j < 4; ++j) {
        f32x4 p = pacc[tslot][j * 64 + lane];
        A[j][0] += p[0]; A[j][1] += p[1]; A[j][2] += p[2]; A[j][3] += p[3];
      }
      if (r < 5)
        epi_h<308, 320>(A, nt, lane, mt, P.bias[0], P.bias[1], P.bias[2], P.bias[3],
                        P.hi + (tstep & 3) * HI_P, vk);
      else if (r < 9)
        epi_h<204, 224>(A, nt, lane, mt, P.bias[4], P.bias[5], P.bias[6], P.bias[7],
                        P.hc + (tstep & 3) * HC_P, vk);
      else
        epi_h<512, 512>(A, nt, lane, mt, P.bias[8], P.bias[9], P.bias[10], P.bias[11],
                        P.hm + (tstep & 3) * HM_P, vk);
    }
    asm volatile("s_waitcnt vmcnt(0)" ::: "memory");
    __syncthreads();                      // (B) all h stores at coherent point
    if (tid == 0) stf(wf + r * 16, (unsigned)(s + 1));

    // ---- off critical path: deferred y/hfin stores (nontemporal) ----
    if (on && role == 0) {
      const int n_ = nt * 16 + (lane & 15);
      const int r0 = (lane >> 4) << 2;
      const int H_ = (r < 5) ? 308 : ((r < 9) ? 204 : 512);
      const int hoff = (r < 5) ? 0 : ((r < 9) ? 308 : 512);
      if (n_ < H_) {
#pragma unroll
        for (int j = 0; j < 4; ++j) {
          const int brow = mt * 16 + r0 + j;
          if (r >= 9)
            __builtin_nontemporal_store(vk[j], &P.y[((size_t)brow * T_STEPS + tstep) * 512 + n_]);
          if (last)
            __builtin_nontemporal_store(vk[j], &P.hfin[brow * 1024 + hoff + n_]);
        }
      }
    }

    // ---- off critical path: L0 prefetches XN(s+1) into other parity ----
    if (r < 5 && s + 1 < T_STEPS)
      stage_xn(Alds + ((s + 1) & 1) * (1024 * 8), P, mt, tid, s + 1);
  }
}

extern "C" void kernel_launch(void* const* d_in, const int* in_sizes, int n_in,
                              void* d_out, int out_size, void* d_ws, size_t ws_size,
                              hipStream_t stream) {
  const float* x     = (const float*)d_in[27];
  const float* h0    = (const float*)d_in[28];
  const float* gamma = (const float*)d_in[29];
  const float* beta  = (const float*)d_in[30];

  char* ws = (char*)d_ws;
  unsigned* bar = (unsigned*)(ws + WS_BAR);
  float* mu   = (float*)(ws + WS_MU);
  float* rstd = (float*)(ws + WS_RSTD);
  ushort_t* hi = (ushort_t*)(ws + WS_HI);
  ushort_t* hc = (ushort_t*)(ws + WS_HC);
  ushort_t* hm = (ushort_t*)(ws + WS_HM);
  ushort_t* pack = (ushort_t*)(ws + WS_PACK);

  float* y = (float*)d_out;
  float* hfin = y + (size_t)64 * 1024 * 512;

  hipMemsetAsync(bar, 0, 16384, stream);

  ln_stats<<<dim3(16384), dim3(256), 0, stream>>>(x, mu, rstd);
  init_h<<<dim3(264), dim3(256), 0, stream>>>(h0, hi, hc, hm);

  PackP pp;
  for (int l = 0; l < 3; ++l) {
    for (int m = 0; m < 4; ++m) pp.w[l * 4 + m] = (const float*)d_in[l * 9 + 2 * m];
    pp.msk[l] = (const float*)d_in[l * 9 + 8];
  }
  pp.pack = pack;
  ncp_pack<<<dim3(1477), dim3(256), 0, stream>>>(pp);

  MainP mp;
  mp.x = x; mp.gamma = gamma; mp.beta = beta;
  for (int l = 0; l < 3; ++l)
    for (int m = 0; m < 4; ++m) mp.bias[l * 4 + m] = (const float*)d_in[l * 9 + 2 * m + 1];
  mp.mu = mu; mp.rstd = rstd;
  mp.hi = hi; mp.hc = hc; mp.hm = hm;
  mp.pack = pack; mp.bar = bar;
  mp.y = y; mp.hfin = hfin;
  ncp_main<<<dim3(NWG), dim3(512), 0, stream>>>(mp);
}

// Round 18
// 6656.293 us; speedup vs baseline: 1.6411x; 1.6411x over previous
//
#include <hip/hip_runtime.h>

typedef __attribute__((ext_vector_type(8))) short short8;
typedef __attribute__((ext_vector_type(4))) float f32x4;
typedef unsigned short ushort_t;
typedef unsigned long long u64_t;

#define T_STEPS 1024
#define NWG 132
#define NWG_MT 33

// r18 = r15 (256-thr WGs, 33/mtile, 2 tiles/WG, wave-pair K-split, weights in
// registers, 4-deep h buffers) + two changes:
//  (1) 2-SLOT INTER-LAYER LAG: L0@s->step s, L1@s->step s-2, L2@s->step s-4.
//      Cross-layer waits relax to >= s-1 (flag posted a full slot earlier ->
//      detect off critical path). Own-layer recurrence stays >= s (inherent).
//  (2) PER-WAVE SUB-FLAGS: role-0 waves (wv 0,2) each post wf[r*16 + (wv&2)*4]
//      right after their own vmcnt(0); final __syncthreads removed. Consumer
//      min-combines the 2 sub-flags per WG. wf >= s+1 certifies: stage reads
//      of slot s done (post is after barrier A) AND h stores drained.
// Waits at slot s (poll3, lane-per-WG, min of 2 sub-flags):
//  L0: [0,10)>=s                 ; [10,17)>=s-1   (hi WAR: L1@s-2 read buf s&3)
//  L1: [10,17)>=s (own hc chain) ; [0,10)>=s-1 (hi(s-2) RAW) ; [17,33)>=s-1
//      (hc WAR: L2@s-2 read buf (s-2)&3)
//  L2: [17,33)>=s (own hm chain) ; [10,17)>=s-1 (hc(s-4) RAW; hm WAR own-covered)
// Early-slot audit: all init-state reads come from parity 3 (hi(-1)@L0s0,
// hc(-1)@L1s2, hm(-1)@L2s4); first writes to parity 3 are hi(3)@s3 (needs
// [0,10)>=3 > L0@0 done), hc(3)@s5 (own>=5), hm(3)@s7 (own>=7). All covered.

#define PACK0 0
#define PACK1 1064960            // 20*26*2048
#define PACK2 1517568            // PACK1 + 13*17*2048

#define HI_P (64*320)
#define HC_P (64*224)
#define HM_P (64*512)

// ws offsets (bytes)
#define WS_BAR   0               // 4 mtiles x 4KB spread flags (2 subflags/WG)
#define WS_MU    16384
#define WS_RSTD  278528
#define WS_HI    540672          // 4*HI_P*2 = 163840 -> 704512
#define WS_HC    704512          // 4*HC_P*2 = 114688 -> 819200
#define WS_HM    819200          // 4*HM_P*2 = 262144 -> 1081344
#define WS_PACK  1081344         // + 6049792 -> ends 7131136

__device__ __forceinline__ ushort_t f2bf(float f) {
  union { float f; unsigned u; } un; un.f = f;
  unsigned r = (un.u + 0x7fffu + ((un.u >> 16) & 1u)) >> 16;
  return (ushort_t)r;
}

__device__ __forceinline__ void st2(ushort_t* p, ushort_t v) {
  __hip_atomic_store(p, v, __ATOMIC_RELAXED, __HIP_MEMORY_SCOPE_SYSTEM);
}
__device__ __forceinline__ u64_t ld8(const ushort_t* p) {
  return __hip_atomic_load((const u64_t*)p, __ATOMIC_RELAXED, __HIP_MEMORY_SCOPE_SYSTEM);
}
__device__ __forceinline__ unsigned ldf(const unsigned* p) {
  return __hip_atomic_load(p, __ATOMIC_RELAXED, __HIP_MEMORY_SCOPE_SYSTEM);
}
__device__ __forceinline__ void stf(unsigned* p, unsigned v) {
  __hip_atomic_store(p, v, __ATOMIC_RELAXED, __HIP_MEMORY_SCOPE_SYSTEM);
}

// ---------------- LayerNorm stats ----------------
__global__ __launch_bounds__(256) void ln_stats(const float* __restrict__ x,
                                                float* __restrict__ mu,
                                                float* __restrict__ rstd) {
  const int row = blockIdx.x * 4 + (threadIdx.x >> 6);
  const int lane = threadIdx.x & 63;
  const float* xr = x + (size_t)row * 512;
  float4 v0 = *(const float4*)(xr + lane * 8);
  float4 v1 = *(const float4*)(xr + lane * 8 + 4);
  float s = v0.x + v0.y + v0.z + v0.w + v1.x + v1.y + v1.z + v1.w;
  float q = v0.x*v0.x + v0.y*v0.y + v0.z*v0.z + v0.w*v0.w
          + v1.x*v1.x + v1.y*v1.y + v1.z*v1.z + v1.w*v1.w;
  for (int m = 1; m <= 32; m <<= 1) {
    s += __shfl_xor(s, m, 64);
    q += __shfl_xor(q, m, 64);
  }
  if (lane == 0) {
    float mean = s * (1.f / 512.f);
    float var = q * (1.f / 512.f) - mean * mean;
    mu[row] = mean;
    rstd[row] = rsqrtf(var + 1e-5f);
  }
}

// -------- init hidden state: bf16 linear padded, ALL FOUR parities --------
__global__ void init_h(const float* __restrict__ h0,
                       ushort_t* hi, ushort_t* hc, ushort_t* hm) {
  int i = blockIdx.x * 256 + threadIdx.x;
  if (i >= 64 * 1056) return;
  int b = i / 1056, c = i % 1056;
  if (c < 320) {
    ushort_t v = (c < 308) ? f2bf(h0[b * 1024 + c]) : 0;
#pragma unroll
    for (int p = 0; p < 4; ++p) st2(hi + p * HI_P + b * 320 + c, v);
  } else if (c < 544) {
    int col = c - 320;
    ushort_t v = (col < 204) ? f2bf(h0[b * 1024 + 308 + col]) : 0;
#pragma unroll
    for (int p = 0; p < 4; ++p) st2(hc + p * HC_P + b * 224 + col, v);
  } else {
    int col = c - 544;
    ushort_t v = f2bf(h0[b * 1024 + 512 + col]);
#pragma unroll
    for (int p = 0; p < 4; ++p) st2(hm + p * HM_P + b * 512 + col, v);
  }
}

// ---------------- pack masked weights ----------------
struct PackP {
  const float* w[12];
  const float* msk[3];
  ushort_t* pack;
};

__global__ __launch_bounds__(256) void ncp_pack(PackP P) {
  int u = blockIdx.x * 256 + threadIdx.x;
  int layer, rem, KB, K, H, s0p, s0l, s1l;
  size_t base;
  if (u < 133120)      { layer = 0; rem = u;          KB = 26; K = 820; H = 308; s0p = 512; s0l = 512; s1l = 308; base = PACK0; }
  else if (u < 189696) { layer = 1; rem = u - 133120; KB = 17; K = 512; H = 204; s0p = 320; s0l = 308; s1l = 204; base = PACK1; }
  else if (u < 378112) { layer = 2; rem = u - 189696; KB = 23; K = 716; H = 512; s0p = 224; s0l = 204; s1l = 512; base = PACK2; }
  else return;
  const int lane = rem & 63;
  const int mat = (rem >> 6) & 3;
  const int kb = (rem >> 8) % KB;
  const int nt = (rem >> 8) / KB;
  const float* W = P.w[layer * 4 + mat];
  const float* M = (mat < 2) ? P.msk[layer] : nullptr;
  const int n = nt * 16 + (lane & 15);
  const int kbase = kb * 32 + ((lane >> 4) << 3);
  ushort_t* dst = P.pack + base + (size_t)rem * 8;
#pragma unroll
  for (int j = 0; j < 8; ++j) {
    const int kp = kbase + j;
    int ko;
    if (kp < s0p) ko = (kp < s0l) ? kp : -1;
    else { const int ks = kp - s0p; ko = (ks < s1l) ? (s0l + ks) : -1; }
    float v = 0.f;
    if (n < H && ko >= 0) {
      v = W[(size_t)n * K + ko];
      if (M) v *= M[(size_t)n * K + ko];
    }
    dst[j] = f2bf(v);
  }
}

// ---------------- main persistent kernel ----------------
struct MainP {
  const float* x;
  const float* gamma;
  const float* beta;
  const float* bias[12];
  const float* mu;
  const float* rstd;
  ushort_t* hi;
  ushort_t* hc;
  ushort_t* hm;
  const ushort_t* pack;
  unsigned* bar;
  float* y;
  float* hfin;
};

#define MAXKB 13

template<int KBT>
__device__ __forceinline__ void load_w(const ushort_t* __restrict__ bp, int lane,
                                       short8 (*w)[4]) {
#pragma unroll
  for (int kb = 0; kb < KBT; ++kb) {
    const ushort_t* q = bp + (size_t)kb * 2048 + lane * 8;
    w[kb][0] = *(const short8*)(q);
    w[kb][1] = *(const short8*)(q + 512);
    w[kb][2] = *(const short8*)(q + 1024);
    w[kb][3] = *(const short8*)(q + 1536);
  }
}

template<int KBT>
__device__ __forceinline__ void span_reg(const short8 (*w)[4],
                                         const ushort_t* __restrict__ lds, int lane,
                                         f32x4& a0, f32x4& a1, f32x4& a2, f32x4& a3) {
#pragma unroll
  for (int kb = 0; kb < KBT; ++kb) {
    short8 av = *(const short8*)(lds + (size_t)(kb * 64 + lane) * 8);
    a0 = __builtin_amdgcn_mfma_f32_16x16x32_bf16(av, w[kb][0], a0, 0, 0, 0);
    a1 = __builtin_amdgcn_mfma_f32_16x16x32_bf16(av, w[kb][1], a1, 0, 0, 0);
    a2 = __builtin_amdgcn_mfma_f32_16x16x32_bf16(av, w[kb][2], a2, 0, 0, 0);
    a3 = __builtin_amdgcn_mfma_f32_16x16x32_bf16(av, w[kb][3], a3, 0, 0, 0);
  }
}

template<int H, int STP>
__device__ __forceinline__ void epi_h(const f32x4* A, int nt, int lane, int mtile,
                                      const float* __restrict__ bp1, const float* __restrict__ bp2,
                                      const float* __restrict__ bpa, const float* __restrict__ bpb,
                                      ushort_t* __restrict__ hout, float* vk) {
  const int n = nt * 16 + (lane & 15);
  const int r0 = (lane >> 4) << 2;
#pragma unroll
  for (int j = 0; j < 4; ++j) vk[j] = 0.f;
  if (n < H) {
    float c1 = bp1[n], c2 = bp2[n], ca = bpa[n], cb = bpb[n];
#pragma unroll
    for (int j = 0; j < 4; ++j) {
      int brow = mtile * 16 + r0 + j;
      float sg = 1.f / (1.f + __expf(-(A[2][j] + ca + A[3][j] + cb)));
      float f1 = 1.f - 2.f / (1.f + __expf(2.f * (A[0][j] + c1)));
      float f2 = 1.f - 2.f / (1.f + __expf(2.f * (A[1][j] + c2)));
      float v = f1 * (1.f - sg) + sg * f2;
      vk[j] = v;
      st2(hout + (size_t)brow * STP + n, f2bf(v));
    }
  }
}

template<int S1, int ST1, int S2, int ST2>
__device__ __forceinline__ void stage2(ushort_t* __restrict__ r1, const ushort_t* __restrict__ h1,
                                       ushort_t* __restrict__ r2, const ushort_t* __restrict__ h2,
                                       int tid) {
  constexpr int U1 = S1 * 2, U2 = S2 * 2;
  constexpr int I1 = (U1 + 255) / 256;
  constexpr int I2 = (U2 + 255) / 256;
  u64_t a[I1];
  u64_t b[I2 > 0 ? I2 : 1];
#pragma unroll
  for (int i = 0; i < I1; ++i) {
    const int u = tid + i * 256;
    if ((U1 & 255) == 0 || u < U1) {
      const int slot = u >> 1;
      a[i] = ld8(h1 + (slot & 15) * ST1 + (slot >> 6) * 32 + ((slot >> 4) & 3) * 8 + (u & 1) * 4);
    }
  }
  if constexpr (S2 > 0) {
#pragma unroll
    for (int i = 0; i < I2; ++i) {
      const int u = tid + i * 256;
      if ((U2 & 255) == 0 || u < U2) {
        const int slot = u >> 1;
        b[i] = ld8(h2 + (slot & 15) * ST2 + (slot >> 6) * 32 + ((slot >> 4) & 3) * 8 + (u & 1) * 4);
      }
    }
  }
#pragma unroll
  for (int i = 0; i < I1; ++i) {
    const int u = tid + i * 256;
    if ((U1 & 255) == 0 || u < U1) *(u64_t*)(r1 + (size_t)u * 4) = a[i];
  }
  if constexpr (S2 > 0) {
#pragma unroll
    for (int i = 0; i < I2; ++i) {
      const int u = tid + i * 256;
      if ((U2 & 255) == 0 || u < U2) *(u64_t*)(r2 + (size_t)u * 4) = b[i];
    }
  }
}

__device__ __forceinline__ void stage_xn(ushort_t* __restrict__ XN, const MainP& P,
                                         int mtile, int tid, int t) {
#pragma unroll
  for (int i = 0; i < 4; ++i) {
    const int s = tid + i * 256;
    const int ln = s & 63;
    const int brow = mtile * 16 + (ln & 15);
    const int kbase = (s >> 6) * 32 + ((ln >> 4) << 3);
    const float muv = P.mu[brow * T_STEPS + t];
    const float rsv = P.rstd[brow * T_STEPS + t];
    const f32x4* xr = (const f32x4*)(P.x + ((size_t)brow * T_STEPS + t) * 512 + kbase);
    f32x4 xv0 = __builtin_nontemporal_load(xr);
    f32x4 xv1 = __builtin_nontemporal_load(xr + 1);
    const f32x4 g0 = *(const f32x4*)(P.gamma + kbase);
    const f32x4 g1 = *(const f32x4*)(P.gamma + kbase + 4);
    const f32x4 b0 = *(const f32x4*)(P.beta + kbase);
    const f32x4 b1 = *(const f32x4*)(P.beta + kbase + 4);
    short8 w;
#pragma unroll
    for (int j = 0; j < 4; ++j) w[j] = f2bf((xv0[j] - muv) * rsv * g0[j] + b0[j]);
#pragma unroll
    for (int j = 0; j < 4; ++j) w[4 + j] = f2bf((xv1[j] - muv) * rsv * g1[j] + b1[j]);
    *(short8*)(XN + (size_t)s * 8) = w;
  }
}

// wave poll: up to three flag ranges (range2,3 share need2); each lane owns one
// WG and min-combines its 2 sub-flags (offsets +0, +8); s_sleep(1) backoff.
__device__ __forceinline__ void poll3(const unsigned* wfbase, int lane,
                                      int a1, int c1, unsigned need1,
                                      int a2, int c2, int a3, int c3, unsigned need2) {
  const unsigned* p = wfbase;
  unsigned need = 0;
  bool act = false;
  if (lane < c1)                { p = wfbase + (a1 + lane) * 16;             need = need1; act = true; }
  else if (lane < c1 + c2)      { p = wfbase + (a2 + lane - c1) * 16;        need = need2; act = true; }
  else if (lane < c1 + c2 + c3) { p = wfbase + (a3 + lane - c1 - c2) * 16;   need = need2; act = true; }
  for (;;) {
    unsigned v = 0xFFFFFFFFu;
    if (act) {
      unsigned v0 = ldf(p), v1 = ldf(p + 8);
      v = v0 < v1 ? v0 : v1;
    }
    if (__all((int)(v >= need))) break;
    __builtin_amdgcn_s_sleep(1);
  }
}

__global__ __launch_bounds__(256, 1) void ncp_main(MainP P) {
  const int tid = threadIdx.x;
  const int lane = tid & 63;
  const int wv = tid >> 6;
  const int role = wv & 1;
  const int tslot = wv >> 1;
  const int wg = blockIdx.x;
  const int mt = wg / NWG_MT;     // 0..3
  const int r  = wg % NWG_MT;     // 0..9: L0, 10..16: L1, 17..32: L2

  __shared__ __align__(16) ushort_t Alds[2688 * 8];  // 42 KB staging (L0 layout)
  __shared__ __align__(16) f32x4 pacc[2][256];       // 8 KB partials (dense)

  // ---- spread flags: 2 sub-flags per WG at wf[r*16] and wf[r*16+8] ----
  unsigned* wf = P.bar + mt * 1024;
  int a1, c1, a2, c2, a3, c3;     // (a1,c1)@>=s ; (a2,c2)+(a3,c3)@>=s-1
  if (r < 10)      { a1 = 0;  c1 = 10; a2 = 10; c2 = 7;  a3 = 0; c3 = 0;  }
  else if (r < 17) { a1 = 10; c1 = 7;  a2 = 0;  c2 = 10; a3 = 17; c3 = 16; }
  else             { a1 = 17; c1 = 16; a2 = 10; c2 = 7;  a3 = 0; c3 = 0;  }

  // ---- per-wave tile/validity ----
  int nt = 0;
  bool valid = true;
  if (r < 10)      nt = r * 2 + tslot;
  else if (r < 17) { nt = (r - 10) * 2 + tslot; valid = (nt < 13); }
  else             nt = (r - 17) * 2 + tslot;

  // ---- one-time weight preload into registers (r13 spans) ----
  short8 wreg[MAXKB][4];
  if (valid) {
    if (r < 10) {
      const ushort_t* bp = P.pack + PACK0 + (size_t)nt * 26 * 2048 + (role ? 13 : 0) * 2048;
      load_w<13>(bp, lane, wreg);
    } else if (r < 17) {
      const ushort_t* bp = P.pack + PACK1 + (size_t)nt * 17 * 2048;
      if (role == 0) load_w<9>(bp, lane, wreg);
      else           load_w<8>(bp + 9 * 2048, lane, wreg);
    } else {
      const ushort_t* bp = P.pack + PACK2 + (size_t)nt * 23 * 2048;
      if (role == 0) load_w<12>(bp, lane, wreg);
      else           load_w<11>(bp + 12 * 2048, lane, wreg);
    }
  }

  if (r < 10) stage_xn(Alds, P, mt, tid, 0);  // prologue XN(0) into parity-0

  for (int s = 0; s < T_STEPS + 4; ++s) {
    // ---- pre-wait: own-layer >= s ; cross-layer/WAR >= s-1 ----
    if (wv == 0) {
      const unsigned needA = (unsigned)s;
      const unsigned needB = (s >= 1) ? (unsigned)(s - 1) : 0u;
      poll3(wf, lane, a1, c1, needA, a2, c2, a3, c3, needB);
    }
    __syncthreads();

    // ---- per-layer slot state (2-slot inter-layer lag) ----
    int tstep = 0;
    bool on = false;
    if (r < 10)      { tstep = s;     on = (s < T_STEPS); }
    else if (r < 17) { tstep = s - 2; on = (s >= 2 && s < T_STEPS + 2) && valid; }
    else             { tstep = s - 4; on = (s >= 4); }
    const bool last = (tstep == T_STEPS - 1);

    // ---- stage (4-deep parity = step mod 4) ----
    if (r < 10) {
      if (s < T_STEPS)
        stage2<640, 320, 0, 0>(Alds + 2048 * 8,
                               P.hi + (((s - 1) & 3) * 64 + mt * 16) * 320,
                               nullptr, nullptr, tid);
    } else if (r < 17) {
      if (s >= 2 && s < T_STEPS + 2)
        stage2<640, 320, 448, 224>(Alds, P.hi + (((s - 2) & 3) * 64 + mt * 16) * 320,
                                   Alds + 640 * 8,
                                   P.hc + (((s - 3) & 3) * 64 + mt * 16) * 224, tid);
    } else {
      if (s >= 4)
        stage2<448, 224, 1024, 512>(Alds, P.hc + (((s - 4) & 3) * 64 + mt * 16) * 224,
                                    Alds + 448 * 8,
                                    P.hm + (((s - 5) & 3) * 64 + mt * 16) * 512, tid);
    }
    __syncthreads();                      // (A) LDS staged

    // ---- spans (register-resident weights) ----
    f32x4 A[4];
#pragma unroll
    for (int j = 0; j < 4; ++j) A[j] = {0.f, 0.f, 0.f, 0.f};
    if (on) {
      if (r < 10) {
        const ushort_t* XNc = Alds + (s & 1) * (1024 * 8);
        const ushort_t* HIl = Alds + 2048 * 8;
        if (role == 0) span_reg<13>(wreg, XNc, lane, A[0], A[1], A[2], A[3]);
        else { span_reg<3>(wreg, XNc + 13 * 512, lane, A[0], A[1], A[2], A[3]);
               span_reg<10>(wreg + 3, HIl, lane, A[0], A[1], A[2], A[3]); }
      } else if (r < 17) {
        const ushort_t* HIr = Alds;
        const ushort_t* HCr = Alds + 640 * 8;
        if (role == 0) span_reg<9>(wreg, HIr, lane, A[0], A[1], A[2], A[3]);
        else { span_reg<1>(wreg, HIr + 9 * 512, lane, A[0], A[1], A[2], A[3]);
               span_reg<7>(wreg + 1, HCr, lane, A[0], A[1], A[2], A[3]); }
      } else {
        const ushort_t* HCr = Alds;
        const ushort_t* HMr = Alds + 448 * 8;
        if (role == 0) { span_reg<7>(wreg, HCr, lane, A[0], A[1], A[2], A[3]);
                         span_reg<5>(wreg + 7, HMr, lane, A[0], A[1], A[2], A[3]); }
        else           span_reg<11>(wreg, HMr + 5 * 512, lane, A[0], A[1], A[2], A[3]);
      }
      if (role == 1) {
#pragma unroll
        for (int j = 0; j < 4; ++j) pacc[tslot][j * 64 + lane] = A[j];
      }
    }
    __syncthreads();                      // (A2) partner accumulator ready

    // ---- epilogue: h-stores; each role-0 wave posts its sub-flag after its
    //      own drain (no trailing barrier) ----
    float vk[4];
    if (on && role == 0) {
#pragma unroll
      for (int j = 0; j < 4; ++j) {
        f32x4 p = pacc[tslot][j * 64 + lane];
        A[j][0] += p[0]; A[j][1] += p[1]; A[j][2] += p[2]; A[j][3] += p[3];
      }
      if (r < 10)
        epi_h<308, 320>(A, nt, lane, mt, P.bias[0], P.bias[1], P.bias[2], P.bias[3],
                        P.hi + (tstep & 3) * HI_P, vk);
      else if (r < 17)
        epi_h<204, 224>(A, nt, lane, mt, P.bias[4], P.bias[5], P.bias[6], P.bias[7],
                        P.hc + (tstep & 3) * HC_P, vk);
      else
        epi_h<512, 512>(A, nt, lane, mt, P.bias[8], P.bias[9], P.bias[10], P.bias[11],
                        P.hm + (tstep & 3) * HM_P, vk);
    }
    if (role == 0) {
      asm volatile("s_waitcnt vmcnt(0)" ::: "memory");   // drain own h stores
      if (lane == 0) stf(wf + r * 16 + (wv & 2) * 4, (unsigned)(s + 1));
    }

    // ---- off critical path: deferred y/hfin stores (nontemporal) ----
    if (on && role == 0) {
      const int n_ = nt * 16 + (lane & 15);
      const int r0 = (lane >> 4) << 2;
      const int H_ = (r < 10) ? 308 : ((r < 17) ? 204 : 512);
      const int hoff = (r < 10) ? 0 : ((r < 17) ? 308 : 512);
      if (n_ < H_) {
#pragma unroll
        for (int j = 0; j < 4; ++j) {
          const int brow = mt * 16 + r0 + j;
          if (r >= 17)
            __builtin_nontemporal_store(vk[j], &P.y[((size_t)brow * T_STEPS + tstep) * 512 + n_]);
          if (last)
            __builtin_nontemporal_store(vk[j], &P.hfin[brow * 1024 + hoff + n_]);
        }
      }
    }

    // ---- off critical path: L0 prefetches XN(s+1) into other parity ----
    if (r < 10 && s + 1 < T_STEPS)
      stage_xn(Alds + ((s + 1) & 1) * (1024 * 8), P, mt, tid, s + 1);
  }
}

extern "C" void kernel_launch(void* const* d_in, const int* in_sizes, int n_in,
                              void* d_out, int out_size, void* d_ws, size_t ws_size,
                              hipStream_t stream) {
  const float* x     = (const float*)d_in[27];
  const float* h0    = (const float*)d_in[28];
  const float* gamma = (const float*)d_in[29];
  const float* beta  = (const float*)d_in[30];

  char* ws = (char*)d_ws;
  unsigned* bar = (unsigned*)(ws + WS_BAR);
  float* mu   = (float*)(ws + WS_MU);
  float* rstd = (float*)(ws + WS_RSTD);
  ushort_t* hi = (ushort_t*)(ws + WS_HI);
  ushort_t* hc = (ushort_t*)(ws + WS_HC);
  ushort_t* hm = (ushort_t*)(ws + WS_HM);
  ushort_t* pack = (ushort_t*)(ws + WS_PACK);

  float* y = (float*)d_out;
  float* hfin = y + (size_t)64 * 1024 * 512;

  hipMemsetAsync(bar, 0, 16384, stream);

  ln_stats<<<dim3(16384), dim3(256), 0, stream>>>(x, mu, rstd);
  init_h<<<dim3(264), dim3(256), 0, stream>>>(h0, hi, hc, hm);

  PackP pp;
  for (int l = 0; l < 3; ++l) {
    for (int m = 0; m < 4; ++m) pp.w[l * 4 + m] = (const float*)d_in[l * 9 + 2 * m];
    pp.msk[l] = (const float*)d_in[l * 9 + 8];
  }
  pp.pack = pack;
  ncp_pack<<<dim3(1477), dim3(256), 0, stream>>>(pp);

  MainP mp;
  mp.x = x; mp.gamma = gamma; mp.beta = beta;
  for (int l = 0; l < 3; ++l)
    for (int m = 0; m < 4; ++m) mp.bias[l * 4 + m] = (const float*)d_in[l * 9 + 2 * m + 1];
  mp.mu = mu; mp.rstd = rstd;
  mp.hi = hi; mp.hc = hc; mp.hm = hm;
  mp.pack = pack; mp.bar = bar;
  mp.y = y; mp.hfin = hfin;
  ncp_main<<<dim3(NWG), dim3(256), 0, stream>>>(mp);
}